// Round 1
// baseline (415.775 us; speedup 1.0000x reference)
//
#include <hip/hip_runtime.h>
#include <cstdint>
#include <cmath>

#define BATCH 16
#define NBOX  131072
#define K_SEL 2048
#define CAND_CAP 4096
#define NMS_MAX 300
#define IOU_THR 0.7f

typedef unsigned int u32;
typedef unsigned long long u64;

// Decode one box exactly like the reference (no fma contraction; exp in double
// ~= correctly-rounded f32 exp, within 1 ulp of numpy).
__device__ __forceinline__ void decode_box(const float* __restrict__ deltas,
                                           const float* __restrict__ anchors,
                                           int b, u32 i,
                                           float& o0, float& o1, float& o2, float& o3) {
  const float4 d = reinterpret_cast<const float4*>(deltas)[(size_t)b * NBOX + i];
  const float4 a = reinterpret_cast<const float4*>(anchors)[i];
  float x = __fadd_rn(__fmul_rn(d.x, a.z), a.x);
  float y = __fadd_rn(__fmul_rn(d.y, a.w), a.y);
  float w = __fmul_rn((float)exp((double)d.z), a.z);
  float h = __fmul_rn((float)exp((double)d.w), a.w);
  o0 = fminf(fmaxf(x, 0.0f), 1333.0f);
  o1 = fminf(fmaxf(y, 0.0f), 1333.0f);
  o2 = fminf(fmaxf(w, 0.0f), 1333.0f);
  o3 = fminf(fmaxf(h, 0.0f), 1333.0f);
}

// One block per batch: exact radix-select of the K_SEL-th largest score,
// compact all scores >= T (ties included), bitonic sort composite keys
// (score_bits<<32 | ~idx  => score desc, idx asc on ties, matching jnp.argmax
// first-occurrence), then gather+decode candidate boxes into SoA.
__global__ __launch_bounds__(1024) void select_kernel(
    const float* __restrict__ probs,
    const float* __restrict__ deltas, const float* __restrict__ anchors,
    float* __restrict__ cc0, float* __restrict__ cc1, float* __restrict__ cc2,
    float* __restrict__ cc3, float* __restrict__ cca, int* __restrict__ meta)
{
  const int b = blockIdx.x;
  const int tid = threadIdx.x;
  const float* __restrict__ pb = probs + (size_t)b * NBOX * 2;

  __shared__ u32 hist[256];
  __shared__ u32 sh_prefix;
  __shared__ int sh_krem;
  __shared__ u32 sh_cnt;
  __shared__ u64 keys[CAND_CAP];

  // ---- exact radix select (scores are softmax outputs >= 0, so the raw f32
  // bit pattern is order-isomorphic to the value) ----
  u32 prefix = 0, pmask = 0;
  int krem = K_SEL;
  for (int p = 3; p >= 0; --p) {
    for (int d = tid; d < 256; d += 1024) hist[d] = 0;
    __syncthreads();
    const int sh = p * 8;
    for (int i = tid; i < NBOX; i += 1024) {
      u32 v = __float_as_uint(pb[(size_t)i * 2 + 1]);
      if ((v & pmask) == prefix) atomicAdd(&hist[(v >> sh) & 255u], 1u);
    }
    __syncthreads();
    if (tid == 0) {
      int cum = 0; int dsel = 0;
      for (int d = 255; d >= 0; --d) {
        cum += (int)hist[d];
        if (cum >= krem) { dsel = d; break; }
      }
      sh_prefix = prefix | ((u32)dsel << sh);
      sh_krem = krem - (cum - (int)hist[dsel]);
    }
    __syncthreads();
    prefix = sh_prefix;
    krem = sh_krem;
    pmask |= (0xFFu << sh);
    __syncthreads();
  }
  const u32 T = prefix;  // K_SEL-th largest score bits

  // ---- compact all candidates with score >= T ----
  if (tid == 0) sh_cnt = 0;
  __syncthreads();
  for (int i = tid; i < NBOX; i += 1024) {
    u32 v = __float_as_uint(pb[(size_t)i * 2 + 1]);
    if (v >= T) {
      u32 pos = atomicAdd(&sh_cnt, 1u);
      if (pos < CAND_CAP) keys[pos] = ((u64)v << 32) | (u64)(~(u32)i);
    }
  }
  __syncthreads();
  const u32 M = min(sh_cnt, (u32)CAND_CAP);
  for (int i = tid; i < CAND_CAP; i += 1024)
    if ((u32)i >= M) keys[i] = 0ull;
  __syncthreads();

  // ---- bitonic sort, descending (unique keys => deterministic) ----
  for (u32 k = 2; k <= (u32)CAND_CAP; k <<= 1) {
    for (u32 j = k >> 1; j > 0; j >>= 1) {
      for (u32 i = tid; i < (u32)CAND_CAP; i += 1024) {
        u32 ixj = i ^ j;
        if (ixj > i) {
          u64 a = keys[i], c = keys[ixj];
          bool desc = ((i & k) == 0);
          bool sw = desc ? (a < c) : (a > c);
          if (sw) { keys[i] = c; keys[ixj] = a; }
        }
      }
      __syncthreads();
    }
  }

  // ---- gather + decode candidate boxes into SoA ----
  for (int s = tid; s < CAND_CAP; s += 1024) {
    float o0, o1, o2, o3, ar;
    if ((u32)s < M) {
      u64 key = keys[s];
      u32 orig = ~((u32)(key & 0xFFFFFFFFull));
      decode_box(deltas, anchors, b, orig, o0, o1, o2, o3);
      ar = __fmul_rn(__fsub_rn(o2, o0), __fsub_rn(o3, o1));
    } else {
      // pad: never scanned (scan limit is M), values irrelevant
      o0 = o1 = 3.0e38f; o2 = o3 = -3.0e38f; ar = 0.0f;
    }
    size_t idx = (size_t)b * CAND_CAP + s;
    cc0[idx] = o0; cc1[idx] = o1; cc2[idx] = o2; cc3[idx] = o3; cca[idx] = ar;
  }
  if (tid == 0) meta[b] = (int)M;
}

// One wave per batch: sequential greedy NMS over sorted candidates.
// Kept list (<=300) lives in per-lane registers: slot s owned by lane s&63,
// register s>>6 (static unrolled indexing so it stays in VGPRs).
__global__ __launch_bounds__(64) void nms_kernel(
    const float* __restrict__ cc0, const float* __restrict__ cc1,
    const float* __restrict__ cc2, const float* __restrict__ cc3,
    const float* __restrict__ cca, const int* __restrict__ meta,
    const float* __restrict__ deltas, const float* __restrict__ anchors,
    float* __restrict__ out)
{
  const int b = blockIdx.x;
  const int lane = threadIdx.x;
  const int M = min(meta[b], CAND_CAP);
  const size_t base = (size_t)b * CAND_CAP;
  const float* __restrict__ C0 = cc0 + base;
  const float* __restrict__ C1 = cc1 + base;
  const float* __restrict__ C2 = cc2 + base;
  const float* __restrict__ C3 = cc3 + base;
  const float* __restrict__ CA = cca + base;

  float k0[5], k1[5], k2[5], k3[5], ka[5];
  __shared__ int keep_slot[NMS_MAX];
  int kept = 0;

  for (int i = 0; i < M; ++i) {
    if (kept >= NMS_MAX) break;
    float b0 = C0[i], b1 = C1[i], b2 = C2[i], b3 = C3[i], ba = CA[i];
    bool sup = false;
#pragma unroll
    for (int r = 0; r < 5; ++r) {
      if (r * 64 + lane < kept) {
        // exact reference IoU arithmetic (no contraction)
        float iy1 = fmaxf(k0[r], b0);
        float ix1 = fmaxf(k1[r], b1);
        float iy2 = fminf(k2[r], b2);
        float ix2 = fminf(k3[r], b3);
        float ih = fmaxf(__fsub_rn(iy2, iy1), 0.0f);
        float iw = fmaxf(__fsub_rn(ix2, ix1), 0.0f);
        float inter = __fmul_rn(ih, iw);
        float denom = __fsub_rn(__fadd_rn(ka[r], ba), inter);
        float iou = __fdiv_rn(inter, denom);
        sup = sup || (iou > IOU_THR);
      }
    }
    if (__any((int)sup)) continue;  // suppressed by a kept box
    // keep it
#pragma unroll
    for (int r = 0; r < 5; ++r) {
      if ((kept >> 6) == r && (kept & 63) == lane) {
        k0[r] = b0; k1[r] = b1; k2[r] = b2; k3[r] = b3; ka[r] = ba;
      }
    }
    if (lane == 0) keep_slot[kept] = i;
    ++kept;
  }
  __syncthreads();

  // invalid slots replicate box 0 of this batch (reference: idx=0 when !valid)
  float f0, f1, f2, f3;
  decode_box(deltas, anchors, b, 0u, f0, f1, f2, f3);

  for (int s = lane; s < NMS_MAX; s += 64) {
    float o0, o1, o2, o3;
    if (s < kept) {
      int cs = keep_slot[s];
      o0 = C0[cs]; o1 = C1[cs]; o2 = C2[cs]; o3 = C3[cs];
    } else {
      o0 = f0; o1 = f1; o2 = f2; o3 = f3;
    }
    reinterpret_cast<float4*>(out)[(size_t)b * NMS_MAX + s] = make_float4(o0, o1, o2, o3);
    out[BATCH * NMS_MAX * 4 + b * NMS_MAX + s] = (float)b;  // batch index output
  }
  if (lane == 0) out[BATCH * NMS_MAX * 4 + BATCH * NMS_MAX + b] = (float)kept;
}

extern "C" void kernel_launch(void* const* d_in, const int* in_sizes, int n_in,
                              void* d_out, int out_size, void* d_ws, size_t ws_size,
                              hipStream_t stream) {
  const float* probs   = (const float*)d_in[0];  // (B, N, 2)
  const float* deltas  = (const float*)d_in[1];  // (B, N, 4)
  const float* anchors = (const float*)d_in[2];  // (N, 4)
  float* out = (float*)d_out;                    // 24016 f32

  // workspace: 5 SoA arrays of B*CAND_CAP f32 + meta  (~1.3 MB)
  float* cc0 = (float*)d_ws;
  float* cc1 = cc0 + BATCH * CAND_CAP;
  float* cc2 = cc1 + BATCH * CAND_CAP;
  float* cc3 = cc2 + BATCH * CAND_CAP;
  float* cca = cc3 + BATCH * CAND_CAP;
  int*  meta = (int*)(cca + BATCH * CAND_CAP);

  select_kernel<<<dim3(BATCH), dim3(1024), 0, stream>>>(
      probs, deltas, anchors, cc0, cc1, cc2, cc3, cca, meta);
  nms_kernel<<<dim3(BATCH), dim3(64), 0, stream>>>(
      cc0, cc1, cc2, cc3, cca, meta, deltas, anchors, out);
}